// Round 8
// baseline (4026.243 us; speedup 1.0000x reference)
//
#include <hip/hip_runtime.h>

// ---------------------------------------------------------------------------
// GRU decoder w/ attention. Round 8: persistent kernel; attention data in
// REGISTERS (persistent across steps).
// R7 post-mortem: phase C re-read PREB/ctxT/WQ (10MB/step) from LLC (per-XCD
// working set > 4MB L2) -> latency-bound at 4 waves/CU. Now:
//  - C-energy (64 blks): PREB slice lives in 32 bf16x8 REGISTERS per thread
//    (loaded once); per-step reads = h1[b] 1KB + WQ (L2-resident).
//  - D-ctx (64 blks): ctxT column-pair lives in 128 u32 registers; per-step
//    reads = attn[b] 512B + h1[b] 1KB.
//  - WQ repacked [k][(a,a+256)] u32 -> coalesced q GEMV.
//  - chain A->B->C->D, per-b attn flags (single-producer), grid 152.
// ---------------------------------------------------------------------------

typedef unsigned short u16;
typedef unsigned long long u64;
using bf16x8 = __attribute__((ext_vector_type(8))) short;
using f32x4  = __attribute__((ext_vector_type(4))) float;

// ---- f32 workspace offsets ----
#define OFF_EGI    0           // [32][64][1536] emb part of gi0 (+b_ih0)
#define OFF_EREAD  3145728     // [32][64][512]  emb part of readout (+b_read)
#define OFF_CNT    6291456     // counters: 33 x 4 phases x 64 groups x 128B
#define CNT_BYTES  1081344
#define OFF_ATTN   6561792     // rotating attn [33][64][128] f32

// ---- u16 (bf16) offsets relative to (u16*)wsf ----
#define UB_PREB    8388608     // [64*128][512] attn precompute bf16 (+b_pre)
#define UB_WIH0C   18087936    // [1536][512] W_ih0 ctx-half
#define UB_WHH0    18874368    // [1536][512]
#define UB_WHH1    19660800    // [1536][512]
#define UB_WIH1    20447232    // [1536][512]
#define UB_WRO     21233664    // [512][512]  W_read out-cols
#define UB_WRC     21495808    // [512][512]  W_read ctx-cols
#define UB_CTXT    21757952    // [64][128][512] ctx transposed bf16
#define UB_WQ      26050560    // [512][256] u32-PACKED pairs (a, a+256)
// rotating bf16 state shadows: 33 slots x [64][512]; slot 32 = initial state
#define ROT_H0B    26312704
#define ROT_H1B    27394048    // h1 == out
#define ROT_CTXB   28475392    // ends 29556736 u16 (byte 59113472)

#define PH_A   0   // h0[t] ready (8 arrivals, group 0)
#define PH_B   1   // h1/out[t] ready (8 arrivals, group 0)
#define PH_AT  2   // attn[t][b] ready (per-b group, 1 arrival)
#define PH_CT  3   // ctx[t] published (8 groups x 8 arrivals)

// ---- output layout (float offsets into d_out) ----
#define OO_G    0
#define OO_C    524288
#define OO_CP   786432
#define OO_HID  788480
#define OO_AL   854016
#define OO_CTXF 862208

__device__ __forceinline__ float sigm(float x) {
    return 1.0f / (1.0f + __expf(-x));
}
__device__ __forceinline__ float tanh_(float x) {
    x = fmaxf(x, -15.f);
    float e = __expf(-2.0f * x);
    return (1.0f - e) / (1.0f + e);
}
__device__ __forceinline__ u16 f2b(float x) {
    unsigned u = __float_as_uint(x);
    return (u16)((u + 0x7FFFu + ((u >> 16) & 1u)) >> 16);
}
__device__ __forceinline__ float b2f(unsigned u) {
    return __uint_as_float(u << 16);
}
__device__ __forceinline__ float bfe(bf16x8 v, int k) {
    return b2f((unsigned)(unsigned short)v[k]);
}

// ---- write-through (LLC-visible) stores; reads are PLAIN on fresh addrs ----
__device__ __forceinline__ void sta8(void* p, u64 v) {
    __hip_atomic_store((u64*)p, v, __ATOMIC_RELAXED, __HIP_MEMORY_SCOPE_AGENT);
}
__device__ __forceinline__ void sta4(void* p, unsigned v) {
    __hip_atomic_store((unsigned*)p, v, __ATOMIC_RELAXED, __HIP_MEMORY_SCOPE_AGENT);
}

// ---- phase counters: (t,ph,g) each on its own 128B line ----
__device__ __forceinline__ unsigned* cptr(float* wsf, int t, int ph, int g) {
    return (unsigned*)(wsf + OFF_CNT) + ((((t * 4) + ph) * 64 + g) << 5);
}
__device__ __forceinline__ void bar_wait1(unsigned* c, unsigned tgt) {
    if (threadIdx.x == 0) {
        while (__hip_atomic_load(c, __ATOMIC_RELAXED, __HIP_MEMORY_SCOPE_AGENT) < tgt)
            __builtin_amdgcn_s_sleep(1);
    }
    __syncthreads();
}
__device__ __forceinline__ void bar_wait8(unsigned* base, unsigned tgt) {
    if (threadIdx.x < 8) {
        unsigned* c = base + (threadIdx.x << 5);
        while (__hip_atomic_load(c, __ATOMIC_RELAXED, __HIP_MEMORY_SCOPE_AGENT) < tgt)
            __builtin_amdgcn_s_sleep(1);
    }
    __syncthreads();
}
__device__ __forceinline__ void bar_arrive(unsigned* c) {
    asm volatile("s_waitcnt vmcnt(0)" ::: "memory");  // drain write-through stores
    __syncthreads();
    if (threadIdx.x == 0)
        __hip_atomic_fetch_add(c, 1u, __ATOMIC_RELAXED, __HIP_MEMORY_SCOPE_AGENT);
}

// ========== f32 tiled GEMM (upfront only); obf!=null -> bf16-only output ====
__device__ __forceinline__ void gemm64(
    const float* __restrict__ xrow, const float* __restrict__ wrow,
    int kt0, int nkt, float* lds_x, float* lds_w,
    float* __restrict__ outp, int JW, int orow0, int j0,
    const float* __restrict__ addp, int addmode, int addJW,
    u16* __restrict__ obf)
{
    const int tid = threadIdx.x;
    const int tb4 = tid >> 4, tj4 = tid & 15;
    float acc[4][4];
#pragma unroll
    for (int a = 0; a < 4; ++a)
#pragma unroll
        for (int b = 0; b < 4; ++b) acc[a][b] = 0.f;

    for (int kt = kt0; kt < kt0 + nkt; ++kt) {
        const int kb = kt << 6;
        __syncthreads();
        {
            const int rl = tid >> 2;
#pragma unroll
            for (int i = 0; i < 4; ++i) {
                const int kk = ((tid & 3) << 4) + (i << 2);
                float4 xv = *(const float4*)(xrow + kb + kk);
                float4 wv = *(const float4*)(wrow + kb + kk);
                lds_x[(kk + 0) * 64 + rl] = xv.x;
                lds_x[(kk + 1) * 64 + rl] = xv.y;
                lds_x[(kk + 2) * 64 + rl] = xv.z;
                lds_x[(kk + 3) * 64 + rl] = xv.w;
                lds_w[(kk + 0) * 64 + rl] = wv.x;
                lds_w[(kk + 1) * 64 + rl] = wv.y;
                lds_w[(kk + 2) * 64 + rl] = wv.z;
                lds_w[(kk + 3) * 64 + rl] = wv.w;
            }
        }
        __syncthreads();
#pragma unroll 4
        for (int kk = 0; kk < 64; ++kk) {
            float4 xv = *(const float4*)(lds_x + kk * 64 + tb4 * 4);
            float4 wv = *(const float4*)(lds_w + kk * 64 + tj4 * 4);
            acc[0][0] += xv.x * wv.x; acc[0][1] += xv.x * wv.y;
            acc[0][2] += xv.x * wv.z; acc[0][3] += xv.x * wv.w;
            acc[1][0] += xv.y * wv.x; acc[1][1] += xv.y * wv.y;
            acc[1][2] += xv.y * wv.z; acc[1][3] += xv.y * wv.w;
            acc[2][0] += xv.z * wv.x; acc[2][1] += xv.z * wv.y;
            acc[2][2] += xv.z * wv.z; acc[2][3] += xv.z * wv.w;
            acc[3][0] += xv.w * wv.x; acc[3][1] += xv.w * wv.y;
            acc[3][2] += xv.w * wv.z; acc[3][3] += xv.w * wv.w;
        }
    }
#pragma unroll
    for (int ib = 0; ib < 4; ++ib) {
        const int row = tb4 * 4 + ib;
        const int jc = j0 + tj4 * 4;
        float4 r;
        r.x = acc[ib][0]; r.y = acc[ib][1]; r.z = acc[ib][2]; r.w = acc[ib][3];
        if (addmode == 1) {
            float4 bv = *(const float4*)(addp + jc);
            r.x += bv.x; r.y += bv.y; r.z += bv.z; r.w += bv.w;
        } else if (addmode == 2) {
            float4 bv = *(const float4*)(addp + (size_t)(orow0 + row) * addJW + jc);
            r.x += bv.x; r.y += bv.y; r.z += bv.z; r.w += bv.w;
        }
        if (obf) {
            u64 pv = (u64)f2b(r.x) | ((u64)f2b(r.y) << 16)
                   | ((u64)f2b(r.z) << 32) | ((u64)f2b(r.w) << 48);
            *(u64*)(obf + (size_t)(orow0 + row) * 512 + jc) = pv;
        } else {
            *(float4*)(outp + (size_t)(orow0 + row) * JW + jc) = r;
        }
    }
}

// ========== bf16 staging (plain cached loads, XOR-swizzled LDS) ==========
__device__ __forceinline__ void stage_plain(const u16* __restrict__ Xg, u16* sX) {
    const int tid = threadIdx.x;
#pragma unroll
    for (int p = 0; p < 16; ++p) {
        const int chunk = p * 256 + tid;
        const int row = chunk >> 6, cb16 = chunk & 63;
        const int src = row * 1024 + cb16 * 16;
        const int dst = src ^ ((row & 7) << 4);
        *(float4*)((char*)sX + dst) = *(const float4*)((const char*)Xg + src);
    }
}

// ========== single 64-col MFMA tile, K=512 ==========
__device__ __forceinline__ void mfma_tile(const u16* sX, const u16* __restrict__ Wg,
                                          f32x4 acc[4]) {
    const int tid = threadIdx.x;
    const int w = tid >> 6, l15 = tid & 15, lhi = (tid & 63) >> 4;
    const int arow = w * 16 + l15;
    const char* aptr = (const char*)sX;
    const int abase = arow * 1024 + lhi * 16;
    const int aswz = (arow & 7) << 4;
#pragma unroll 4
    for (int ks = 0; ks < 16; ++ks) {
        bf16x8 a = *(const bf16x8*)(aptr + ((abase + ks * 64) ^ aswz));
        const u16* wp = Wg + l15 * 512 + ks * 32 + lhi * 8;
        acc[0] = __builtin_amdgcn_mfma_f32_16x16x32_bf16(a, *(const bf16x8*)(wp), acc[0], 0, 0, 0);
        acc[1] = __builtin_amdgcn_mfma_f32_16x16x32_bf16(a, *(const bf16x8*)(wp + 16*512), acc[1], 0, 0, 0);
        acc[2] = __builtin_amdgcn_mfma_f32_16x16x32_bf16(a, *(const bf16x8*)(wp + 32*512), acc[2], 0, 0, 0);
        acc[3] = __builtin_amdgcn_mfma_f32_16x16x32_bf16(a, *(const bf16x8*)(wp + 48*512), acc[3], 0, 0, 0);
    }
}

// ========== merged 3-gate tile: 12 indep loads + 12 MFMAs per k-slice ==========
__device__ __forceinline__ void mfma_tile3(const u16* sX,
        const u16* __restrict__ W0, const u16* __restrict__ W1,
        const u16* __restrict__ W2, f32x4 a0[4], f32x4 a1[4], f32x4 a2[4]) {
    const int tid = threadIdx.x;
    const int w = tid >> 6, l15 = tid & 15, lhi = (tid & 63) >> 4;
    const int arow = w * 16 + l15;
    const char* aptr = (const char*)sX;
    const int abase = arow * 1024 + lhi * 16;
    const int aswz = (arow & 7) << 4;
#pragma unroll 2
    for (int ks = 0; ks < 16; ++ks) {
        bf16x8 a = *(const bf16x8*)(aptr + ((abase + ks * 64) ^ aswz));
        const int wo = l15 * 512 + ks * 32 + lhi * 8;
        const u16 *p0 = W0 + wo, *p1 = W1 + wo, *p2 = W2 + wo;
        bf16x8 b00 = *(const bf16x8*)(p0),         b01 = *(const bf16x8*)(p0 + 8192);
        bf16x8 b02 = *(const bf16x8*)(p0 + 16384), b03 = *(const bf16x8*)(p0 + 24576);
        bf16x8 b10 = *(const bf16x8*)(p1),         b11 = *(const bf16x8*)(p1 + 8192);
        bf16x8 b12 = *(const bf16x8*)(p1 + 16384), b13 = *(const bf16x8*)(p1 + 24576);
        bf16x8 b20 = *(const bf16x8*)(p2),         b21 = *(const bf16x8*)(p2 + 8192);
        bf16x8 b22 = *(const bf16x8*)(p2 + 16384), b23 = *(const bf16x8*)(p2 + 24576);
        a0[0] = __builtin_amdgcn_mfma_f32_16x16x32_bf16(a, b00, a0[0], 0, 0, 0);
        a0[1] = __builtin_amdgcn_mfma_f32_16x16x32_bf16(a, b01, a0[1], 0, 0, 0);
        a0[2] = __builtin_amdgcn_mfma_f32_16x16x32_bf16(a, b02, a0[2], 0, 0, 0);
        a0[3] = __builtin_amdgcn_mfma_f32_16x16x32_bf16(a, b03, a0[3], 0, 0, 0);
        a1[0] = __builtin_amdgcn_mfma_f32_16x16x32_bf16(a, b10, a1[0], 0, 0, 0);
        a1[1] = __builtin_amdgcn_mfma_f32_16x16x32_bf16(a, b11, a1[1], 0, 0, 0);
        a1[2] = __builtin_amdgcn_mfma_f32_16x16x32_bf16(a, b12, a1[2], 0, 0, 0);
        a1[3] = __builtin_amdgcn_mfma_f32_16x16x32_bf16(a, b13, a1[3], 0, 0, 0);
        a2[0] = __builtin_amdgcn_mfma_f32_16x16x32_bf16(a, b20, a2[0], 0, 0, 0);
        a2[1] = __builtin_amdgcn_mfma_f32_16x16x32_bf16(a, b21, a2[1], 0, 0, 0);
        a2[2] = __builtin_amdgcn_mfma_f32_16x16x32_bf16(a, b22, a2[2], 0, 0, 0);
        a2[3] = __builtin_amdgcn_mfma_f32_16x16x32_bf16(a, b23, a2[3], 0, 0, 0);
    }
}
__device__ __forceinline__ void zero4(f32x4 a[4]) {
    f32x4 z = {0.f, 0.f, 0.f, 0.f};
    a[0] = z; a[1] = z; a[2] = z; a[3] = z;
}

// =================== upfront: all static data + initial state ===============
__global__ __launch_bounds__(256)
void k_upfront(const int* __restrict__ inp, const float* __restrict__ hid,
               const float* __restrict__ ctxin, const float* __restrict__ init_att,
               const float* __restrict__ embW,
               const float* __restrict__ W_ih0, const float* __restrict__ b_ih0,
               const float* __restrict__ W_hh0, const float* __restrict__ W_hh1,
               const float* __restrict__ W_ih1, const float* __restrict__ W_q,
               const float* __restrict__ W_read, const float* __restrict__ b_read,
               const float* __restrict__ W_pre, const float* __restrict__ b_pre,
               float* __restrict__ wsf)
{
    __shared__ float lds_x[4096], lds_w[4096];
    u16* wsu = (u16*)wsf;
    const int jid = blockIdx.x, tid = threadIdx.x, rl = tid >> 2;
    if (jid < 768) {
        const int mt = jid / 24, jt = jid % 24, j0 = jt << 6;
        const int idx = inp[mt * 64 + rl];
        gemm64(embW + (size_t)idx * 512, W_ih0 + (size_t)(j0 + rl) * 1024,
               0, 8, lds_x, lds_w, wsf + OFF_EGI, 1536, mt << 6, j0, b_ih0, 1, 0, nullptr);
    } else if (jid < 1024) {
        const int r = jid - 768, mt = r >> 3, jt = r & 7, j0 = jt << 6;
        const int idx = inp[mt * 64 + rl];
        gemm64(embW + (size_t)idx * 512, W_read + (size_t)(j0 + rl) * 1536,
               0, 8, lds_x, lds_w, wsf + OFF_EREAD, 512, mt << 6, j0, b_read, 1, 0, nullptr);
    } else if (jid < 2048) {
        const int r = jid - 1024, mt = r >> 3, jt = r & 7, j0 = jt << 6;
        const int m = (mt << 6) + rl, b = m >> 7, s = m & 127;
        gemm64(ctxin + (size_t)((s << 6) + b) * 512, W_pre + (size_t)(j0 + rl) * 512,
               0, 8, lds_x, lds_w, nullptr, 512, mt << 6, j0, b_pre, 1, 0,
               wsu + UB_PREB);
    } else if (jid < 2272) {
        const int w = jid - 2048;
        if (w < 48) {
            for (int i = 0; i < 64; ++i) {
                int e = w * 16384 + i * 256 + tid;
                int j = e >> 9, k = e & 511;
                wsu[UB_WIH0C + e] = f2b(W_ih0[(size_t)j * 1024 + 512 + k]);
            }
        } else if (w < 96) {
            for (int i = 0; i < 64; ++i) {
                int e = (w - 48) * 16384 + i * 256 + tid;
                wsu[UB_WHH0 + e] = f2b(W_hh0[e]);
            }
        } else if (w < 144) {
            for (int i = 0; i < 64; ++i) {
                int e = (w - 96) * 16384 + i * 256 + tid;
                wsu[UB_WHH1 + e] = f2b(W_hh1[e]);
            }
        } else if (w < 192) {
            for (int i = 0; i < 64; ++i) {
                int e = (w - 144) * 16384 + i * 256 + tid;
                wsu[UB_WIH1 + e] = f2b(W_ih1[e]);
            }
        } else if (w < 208) {
            for (int i = 0; i < 64; ++i) {
                int e = (w - 192) * 16384 + i * 256 + tid;
                int j = e >> 9, k = e & 511;
                wsu[UB_WRO + e] = f2b(W_read[(size_t)j * 1536 + 512 + k]);
            }
        } else {
            for (int i = 0; i < 64; ++i) {
                int e = (w - 208) * 16384 + i * 256 + tid;
                int j = e >> 9, k = e & 511;
                wsu[UB_WRC + e] = f2b(W_read[(size_t)j * 1536 + 1024 + k]);
            }
        }
    } else if (jid < 2528) {
        // ctxT bf16 [b][s][e]
        const int w2 = jid - 2272;
        for (int rr = 0; rr < 32; ++rr) {
            const int r = w2 * 32 + rr;
            const int b = r >> 7, s = r & 127;
            const float* src = ctxin + ((size_t)s * 64 + b) * 512;
#pragma unroll
            for (int h = 0; h < 2; ++h) {
                int e = h * 256 + tid;
                wsu[UB_CTXT + (size_t)r * 512 + e] = f2b(src[e]);
            }
        }
    } else if (jid < 2544) {
        // WQ packed: [k][2*a2 + hi] = W_q[(a2 + hi*256)][k]
        const int w3 = jid - 2528;
        for (int i = 0; i < 64; ++i) {
            int e = w3 * 16384 + i * 256 + tid;
            int k = e >> 9, rem = e & 511, a2 = rem >> 1, hi = rem & 1;
            wsu[UB_WQ + e] = f2b(W_q[(size_t)(a2 + hi * 256) * 512 + k]);
        }
    } else {
        // initial bf16 states into rotation slot 32
        const int job = jid - 2544;
        const float* src = job == 0 ? hid : (job == 1 ? hid + 32768 : init_att);
        u16* dst = wsu + (size_t)(job == 0 ? ROT_H0B : (job == 1 ? ROT_H1B : ROT_CTXB))
                 + (size_t)32 * 32768;
        for (int i = 0; i < 128; ++i) {
            int e = i * 256 + tid;
            dst[e] = f2b(src[e]);
        }
    }
}

// =================== persistent loop kernel (152 blocks) ===================
__global__ __launch_bounds__(256, 1)
void k_loop(const float* __restrict__ b_hh0, const float* __restrict__ b_ih1,
            const float* __restrict__ b_hh1, const float* __restrict__ hid,
            const float* __restrict__ maskp, const float* __restrict__ w_v,
            const float* __restrict__ W_copy, const float* __restrict__ b_copy,
            float* __restrict__ wsf, float* __restrict__ dout)
{
    __shared__ u16 sX[32768];   // 64KB staging / scratch
    u16* wsu = (u16*)wsf;
    const int blk = blockIdx.x, tid = threadIdx.x;
    const int w = tid >> 6, l15 = tid & 15, lhi = (tid & 63) >> 4;

    if (blk < 8) {
        // ===== A: layer-0 gates -> h0[t].  gh0 overlaps prior step. =====
        const int j = blk;
        float hp[4][4];
#pragma unroll
        for (int cb = 0; cb < 4; ++cb)
#pragma unroll
            for (int r = 0; r < 4; ++r)
                hp[cb][r] = hid[(w * 16 + lhi * 4 + r) * 512 + j * 64 + cb * 16 + l15];

        for (int t = 0; t < 32; ++t) {
            const size_t slot = t, slotp = (t == 0) ? 32 : (size_t)(t - 1);
            float eg0[4][4], eg1[4][4], eg2[4][4];
            {
                const float* EG = wsf + OFF_EGI + (size_t)t * 98304;
#pragma unroll
                for (int cb = 0; cb < 4; ++cb) {
                    const int gc = j * 64 + cb * 16 + l15;
#pragma unroll
                    for (int r = 0; r < 4; ++r) {
                        const float* eg = EG + (size_t)(w * 16 + lhi * 4 + r) * 1536;
                        eg0[cb][r] = eg[gc];
                        eg1[cb][r] = eg[512 + gc];
                        eg2[cb][r] = eg[1024 + gc];
                    }
                }
            }
            f32x4 aR[4], aZ[4], aIN[4], aHN[4];
            zero4(aR); zero4(aZ); zero4(aIN); zero4(aHN);
            // gh0: needs h0[t-1] only — overlaps C/D(t-1)
            if (t > 0) bar_wait1(cptr(wsf, t - 1, PH_A, 0), 8);
            stage_plain(wsu + ROT_H0B + slotp * 32768, sX);
            __syncthreads();
            mfma_tile3(sX, wsu + UB_WHH0 + (size_t)(j * 64) * 512,
                           wsu + UB_WHH0 + (size_t)(512 + j * 64) * 512,
                           wsu + UB_WHH0 + (size_t)(1024 + j * 64) * 512, aR, aZ, aHN);
            __syncthreads();
            // gi0: needs ctx[t-1] — the critical wait
            if (t > 0) bar_wait8(cptr(wsf, t - 1, PH_CT, 0), 8);
            stage_plain(wsu + ROT_CTXB + slotp * 32768, sX);
            __syncthreads();
            mfma_tile3(sX, wsu + UB_WIH0C + (size_t)(j * 64) * 512,
                           wsu + UB_WIH0C + (size_t)(512 + j * 64) * 512,
                           wsu + UB_WIH0C + (size_t)(1024 + j * 64) * 512, aR, aZ, aIN);
            __syncthreads();
            u16* tile = sX;
#pragma unroll
            for (int cb = 0; cb < 4; ++cb) {
                const int lc = cb * 16 + l15, gc = j * 64 + lc;
                const float brr = b_hh0[gc], bzz = b_hh0[512 + gc], bnn = b_hh0[1024 + gc];
#pragma unroll
                for (int r = 0; r < 4; ++r) {
                    const int row = w * 16 + lhi * 4 + r;
                    float rr = sigm(aR[cb][r] + eg0[cb][r] + brr);
                    float zz = sigm(aZ[cb][r] + eg1[cb][r] + bzz);
                    float nn = tanh_(aIN[cb][r] + eg2[cb][r] + rr * (aHN[cb][r] + bnn));
                    float v = (1.f - zz) * nn + zz * hp[cb][r];
                    hp[cb][r] = v;
                    tile[row * 64 + lc] = f2b(v);
                    if (t == 31) dout[OO_HID + row * 512 + gc] = v;
                }
            }
            __syncthreads();
            {
                u16* dst = wsu + ROT_H0B + slot * 32768 + j * 64;
#pragma unroll
                for (int i = 0; i < 4; ++i) {
                    int e = i * 256 + tid, row = e >> 4, c = e & 15;
                    sta8(dst + (size_t)row * 512 + c * 4, *(const u64*)(tile + row * 64 + c * 4));
                }
            }
            bar_arrive(cptr(wsf, t, PH_A, 0));
        }
    } else if (blk < 16) {
        // ===== B: layer-1 gates -> h1/out[t].  gh1 overlaps A(t). =====
        const int j = blk - 8;
        float hp[4][4];
#pragma unroll
        for (int cb = 0; cb < 4; ++cb)
#pragma unroll
            for (int r = 0; r < 4; ++r)
                hp[cb][r] = hid[32768 + (w * 16 + lhi * 4 + r) * 512 + j * 64 + cb * 16 + l15];

        for (int t = 0; t < 32; ++t) {
            const size_t slot = t, slotp = (t == 0) ? 32 : (size_t)(t - 1);
            f32x4 aR[4], aZ[4], aIN[4], aHN[4];
            zero4(aR); zero4(aZ); zero4(aIN); zero4(aHN);
            if (t > 0) bar_wait1(cptr(wsf, t - 1, PH_B, 0), 8);
            stage_plain(wsu + ROT_H1B + slotp * 32768, sX);
            __syncthreads();
            mfma_tile3(sX, wsu + UB_WHH1 + (size_t)(j * 64) * 512,
                           wsu + UB_WHH1 + (size_t)(512 + j * 64) * 512,
                           wsu + UB_WHH1 + (size_t)(1024 + j * 64) * 512, aR, aZ, aHN);
            __syncthreads();
            bar_wait1(cptr(wsf, t, PH_A, 0), 8);
            stage_plain(wsu + ROT_H0B + slot * 32768, sX);
            __syncthreads();
            mfma_tile3(sX, wsu + UB_WIH1 + (size_t)(j * 64) * 512,
                           wsu + UB_WIH1 + (size_t)(512 + j * 64) * 512,
                           wsu + UB_WIH1 + (size_t)(1024 + j * 64) * 512, aR, aZ, aIN);
            __syncthreads();
            u16* tile = sX;
#pragma unroll
            for (int cb = 0; cb < 4; ++cb) {
                const int lc = cb * 16 + l15, gc = j * 64 + lc;
                const float bir = b_ih1[gc] + b_hh1[gc];
                const float biz = b_ih1[512 + gc] + b_hh1[512 + gc];
                const float bin_ = b_ih1[1024 + gc];
                const float bhn = b_hh1[1024 + gc];
#pragma unroll
                for (int r = 0; r < 4; ++r) {
                    const int row = w * 16 + lhi * 4 + r;
                    float rr = sigm(aR[cb][r] + bir);
                    float zz = sigm(aZ[cb][r] + biz);
                    float nn = tanh_(aIN[cb][r] + bin_ + rr * (aHN[cb][r] + bhn));
                    float v = (1.f - zz) * nn + zz * hp[cb][r];
                    hp[cb][r] = v;
                    tile[row * 64 + lc] = f2b(v);
                    if (t == 31) dout[OO_HID + 32768 + row * 512 + gc] = v;
                }
            }
            __syncthreads();
            {
                u16* dst = wsu + ROT_H1B + slot * 32768 + j * 64;
#pragma unroll
                for (int i = 0; i < 4; ++i) {
                    int e = i * 256 + tid, row = e >> 4, c = e & 15;
                    sta8(dst + (size_t)row * 512 + c * 4, *(const u64*)(tile + row * 64 + c * 4));
                }
            }
            bar_arrive(cptr(wsf, t, PH_B, 0));
        }
    } else if (blk < 80) {
        // ===== C-energy: PREB in registers; q GEMV; softmax; publish attn ====
        const int b = blk - 16;
        float* sf = (float*)sX;
        float* s_out  = sf;            // 512
        float* s_q    = sf + 512;      // 512
        float* s_e    = sf + 1024;     // 128
        float* s_at   = sf + 1152;     // 128
        float* s_part = sf + 1280;     // 256
        float* s_wv   = sf + 1536;     // 512
        float* s_msk  = sf + 2048;     // 128

        for (int i = tid; i < 512; i += 256) s_wv[i] = w_v[i];
        if (tid < 128) s_msk[tid] = (maskp[b * 128 + tid] > 0.5f) ? -3.0e38f : 0.0f;
        // PREB slice -> registers (persistent across all 32 steps)
        const int sh = tid & 1;
        bf16x8 pr[32];
        {
            const u16* prep = wsu + UB_PREB + (((size_t)b * 128 + (tid >> 1)) << 9) + (sh << 8);
#pragma unroll
            for (int i = 0; i < 32; ++i) pr[i] = *(const bf16x8*)(prep + i * 8);
        }
        __syncthreads();

        for (int t = 0; t < 32; ++t) {
            bar_wait1(cptr(wsf, t, PH_B, 0), 8);
            {   // out[b] = h1[t][b]
                const u16* ob = wsu + ROT_H1B + (size_t)t * 32768 + b * 512;
                const int c0 = tid * 2;
                unsigned pv = *(const unsigned*)(ob + c0);
                s_out[c0] = b2f(pv & 0xffffu);
                s_out[c0 + 1] = b2f(pv >> 16);
            }
            __syncthreads();
            {   // q GEMV: packed WQ [k][(tid, tid+256)], coalesced, L2-resident
                const u16* wq = wsu + UB_WQ + 2 * tid;
                float q0 = 0.f, q1 = 0.f;
#pragma unroll 8
                for (int k = 0; k < 512; ++k) {
                    unsigned pv = *(const unsigned*)(wq + (size_t)k * 512);
                    float ov = s_out[k];
                    q0 = fmaf(ov, b2f(pv & 0xffffu), q0);
                    q1 = fmaf(ov, b2f(pv >> 16), q1);
                }
                s_q[tid] = q0; s_q[tid + 256] = q1;
            }
            __syncthreads();
            {   // energy from registers
                float part = 0.f;
#pragma unroll
                for (int i = 0; i < 32; ++i) {
                    bf16x8 v = pr[i];
#pragma unroll
                    for (int k2 = 0; k2 < 8; ++k2) {
                        const int a = (sh << 8) + i * 8 + k2;
                        part += tanh_(bfe(v, k2) + s_q[a]) * s_wv[a];
                    }
                }
                s_part[tid] = part;
            }
            __syncthreads();
            if (tid < 128) s_e[tid] = s_part[tid * 2] + s_part[tid * 2 + 1] + s_msk[tid];
            __syncthreads();
            if (tid < 64) {   // softmax over S=128
                float e0 = s_e[tid], e1 = s_e[tid + 64];
                float mx = fmaxf(e0, e1);
#pragma unroll
                for (int d2 = 1; d2 < 64; d2 <<= 1) mx = fmaxf(mx, __shfl_xor(mx, d2, 64));
                float x0 = __expf(e0 - mx), x1 = __expf(e1 - mx);
                float sm = x0 + x1;
#pragma unroll
                for (int d2 = 1; d2 < 64; d2 <<= 1) sm += __shfl_xor(sm, d2, 64);
                float inv = 1.f / sm;
                x0 *= inv; x1 *= inv;
                s_at[tid] = x0; s_at[tid + 64] = x1;
                float* co = dout + OO_C + ((size_t)t * 64 + b) * 128;
                co[tid] = x0; co[tid + 64] = x1;
                if (t == 31) {
                    dout[OO_AL + b * 128 + tid] = x0;
                    dout[OO_AL + b * 128 + tid + 64] = x1;
                }
            }
            __syncthreads();
            if (tid < 128)
                sta4((unsigned*)(wsf + OFF_ATTN + (size_t)t * 8192 + b * 128 + tid),
                     __float_as_uint(s_at[tid]));
            bar_arrive(cptr(wsf, t, PH_AT, b));
        }
    } else if (blk < 144) {
        // ===== D-ctx: ctxT column-pair in registers; gather; copy gate =====
        const int b = blk - 80;
        float* sf = (float*)sX;
        float* s_out = sf;          // 512
        float* s_at  = sf + 512;    // 128
        float* s_ctx = sf + 640;    // 512
        float* s_red = sf + 1152;   // 256
        float* s_wcp = sf + 1408;   // 1024

        for (int i = tid; i < 1024; i += 256) s_wcp[i] = W_copy[i];
        unsigned cr[128];
        {
            const u16* ct = wsu + UB_CTXT + (size_t)b * 65536 + tid * 2;
#pragma unroll
            for (int s = 0; s < 128; ++s) cr[s] = *(const unsigned*)(ct + (size_t)s * 512);
        }
        __syncthreads();

        for (int t = 0; t < 32; ++t) {
            bar_wait1(cptr(wsf, t, PH_B, 0), 8);
            {   // out[b] for copy gate (overlaps C's work)
                const u16* ob = wsu + ROT_H1B + (size_t)t * 32768 + b * 512;
                const int c0 = tid * 2;
                unsigned pv = *(const unsigned*)(ob + c0);
                s_out[c0] = b2f(pv & 0xffffu);
                s_out[c0 + 1] = b2f(pv >> 16);
            }
            bar_wait1(cptr(wsf, t, PH_AT, b), 1);
            if (tid < 128) s_at[tid] = wsf[OFF_ATTN + (size_t)t * 8192 + b * 128 + tid];
            __syncthreads();
            {   // ctx gather from registers
                float a0 = 0.f, a1 = 0.f;
#pragma unroll
                for (int s = 0; s < 128; ++s) {
                    float at = s_at[s];
                    unsigned pv = cr[s];
                    a0 = fmaf(at, b2f(pv & 0xffffu), a0);
                    a1 = fmaf(at, b2f(pv >> 16), a1);
                }
                const int e0 = tid * 2;
                s_ctx[e0] = a0; s_ctx[e0 + 1] = a1;
                sta4(wsu + ROT_CTXB + (size_t)t * 32768 + b * 512 + e0,
                     (unsigned)f2b(a0) | ((unsigned)f2b(a1) << 16));
                if (t == 31) {
                    dout[OO_CTXF + b * 512 + e0] = a0;
                    dout[OO_CTXF + b * 512 + e0 + 1] = a1;
                }
            }
            bar_arrive(cptr(wsf, t, PH_CT, b >> 3));
            {   // copy gate (off critical path)
                const int i2 = tid * 2;
                float part = s_out[i2] * s_wcp[i2] + s_ctx[i2] * s_wcp[512 + i2]
                           + s_out[i2 + 1] * s_wcp[i2 + 1] + s_ctx[i2 + 1] * s_wcp[512 + i2 + 1];
                s_red[tid] = part;
                __syncthreads();
                for (int d2 = 128; d2 > 0; d2 >>= 1) {
                    if (tid < d2) s_red[tid] += s_red[tid + d2];
                    __syncthreads();
                }
                if (tid == 0)
                    dout[OO_CP + t * 64 + b] = sigm(s_red[0] + b_copy[0]);
            }
        }
    } else {
        // ============ RO+maxout track (8 blocks, off critical path) ============
        const int j = blk - 144;
        for (int tp = 0; tp < 32; ++tp) {
            bar_wait1(cptr(wsf, tp, PH_B, 0), 8);
            stage_plain(wsu + ROT_H1B + (size_t)tp * 32768, sX);
            __syncthreads();
            f32x4 acc[4];
            zero4(acc);
            mfma_tile(sX, wsu + UB_WRO + (size_t)(j * 64) * 512, acc);
            bar_wait8(cptr(wsf, tp, PH_CT, 0), 8);
            __syncthreads();
            stage_plain(wsu + ROT_CTXB + (size_t)tp * 32768, sX);
            __syncthreads();
            mfma_tile(sX, wsu + UB_WRC + (size_t)(j * 64) * 512, acc);
            __syncthreads();
            float* ft = (float*)sX;
            const float* ER = wsf + OFF_EREAD + (size_t)tp * 32768;
#pragma unroll
            for (int cb = 0; cb < 4; ++cb) {
                const int lc = cb * 16 + l15;
#pragma unroll
                for (int r = 0; r < 4; ++r) {
                    const int row = w * 16 + lhi * 4 + r;
                    ft[row * 64 + lc] = acc[cb][r] + ER[(size_t)row * 512 + j * 64 + lc];
                }
            }
            __syncthreads();
#pragma unroll
            for (int i = 0; i < 8; ++i) {
                int e = i * 256 + tid, row = e >> 5, c2 = e & 31;
                dout[OO_G + (size_t)tp * 16384 + row * 256 + j * 32 + c2] =
                    fmaxf(ft[row * 64 + 2 * c2], ft[row * 64 + 2 * c2 + 1]);
            }
        }
    }
}

extern "C" void kernel_launch(void* const* d_in, const int* in_sizes, int n_in,
                              void* d_out, int out_size, void* d_ws, size_t ws_size,
                              hipStream_t stream) {
    const int*   inp      = (const int*)d_in[0];
    const float* hid      = (const float*)d_in[1];
    const float* ctxin    = (const float*)d_in[2];
    const float* maskp    = (const float*)d_in[3];
    const float* init_att = (const float*)d_in[4];
    const float* embW     = (const float*)d_in[5];
    const float* W_ih0    = (const float*)d_in[6];
    const float* b_ih0    = (const float*)d_in[7];
    const float* W_hh0    = (const float*)d_in[8];
    const float* b_hh0    = (const float*)d_in[9];
    const float* W_ih1    = (const float*)d_in[10];
    const float* b_ih1    = (const float*)d_in[11];
    const float* W_hh1    = (const float*)d_in[12];
    const float* b_hh1    = (const float*)d_in[13];
    const float* W_pre    = (const float*)d_in[14];
    const float* b_pre    = (const float*)d_in[15];
    const float* W_q      = (const float*)d_in[16];
    const float* w_v      = (const float*)d_in[17];
    const float* W_copy   = (const float*)d_in[18];
    const float* b_copy   = (const float*)d_in[19];
    const float* W_read   = (const float*)d_in[20];
    const float* b_read   = (const float*)d_in[21];
    float* dout = (float*)d_out;
    float* wsf  = (float*)d_ws;

    // zero the phase counters each call (byte offset OFF_CNT*4)
    hipMemsetAsync((char*)d_ws + (size_t)OFF_CNT * 4, 0, CNT_BYTES, stream);

    k_upfront<<<dim3(2547), dim3(256), 0, stream>>>(
        inp, hid, ctxin, init_att, embW, W_ih0, b_ih0, W_hh0, W_hh1, W_ih1, W_q,
        W_read, b_read, W_pre, b_pre, wsf);

    k_loop<<<dim3(152), dim3(256), 0, stream>>>(
        b_hh0, b_ih1, b_hh1, hid, maskp, w_v, W_copy, b_copy, wsf, dout);
}